// Round 4
// baseline (5159.996 us; speedup 1.0000x reference)
//
#include <hip/hip_runtime.h>

typedef _Float16 half8 __attribute__((ext_vector_type(8)));
typedef _Float16 half4 __attribute__((ext_vector_type(4)));
typedef float f32x4 __attribute__((ext_vector_type(4)));

#define NSTEP 48
#define MT 16
#define LDX 264    // x row stride (halfs)
#define LDH0 296   // h0 + ext(sn+zeros) row stride
#define LDH1 264

// LDS-only barrier: does NOT drain vmcnt -> weight prefetch stays in flight.
// sched_barrier(0) fences compiler reordering around the inline-asm wait.
#define BAR() do { asm volatile("s_waitcnt lgkmcnt(0)" ::: "memory"); \
                   __builtin_amdgcn_s_barrier();                      \
                   __builtin_amdgcn_sched_barrier(0); } while (0)

__device__ __forceinline__ float sigm(float x) { return 1.0f / (1.0f + __expf(-x)); }
__device__ __forceinline__ float tanh_f(float x) {
  float ax = fabsf(x);
  float e = __expf(-2.0f * ax);
  float t = (1.0f - e) / (1.0f + e);
  return copysignf(t, x);
}

// Fragment-order packed weights (coalesced: one 1KB contiguous block per (w,kt,c)):
//   W0p[w][kt(17)][c(4)][lane(64)=(q<<4|r)][j(8)] = W0[c*256 + w*16 + r][kt*32 + q*8 + j]
//     where W0 K-layout = [256 x-feat | 256 h0 | 3 shifted-notes | 29 zeros]
//   W1p[w][kt(16)][c][lane][j] = W1[c*256 + w*16 + r][kt*32 + q*8 + j], K = [256 h0new | 256 h1]
__global__ void prep_weights(const float* __restrict__ Wih0, const float* __restrict__ Whh0,
                             const float* __restrict__ bih0, const float* __restrict__ bhh0,
                             const float* __restrict__ Wih1, const float* __restrict__ Whh1,
                             const float* __restrict__ bih1, const float* __restrict__ bhh1,
                             _Float16* __restrict__ W0p, _Float16* __restrict__ W1p,
                             float* __restrict__ b0, float* __restrict__ b1) {
  int n = blockIdx.x;              // gate-row 0..1023
  int c = n >> 8, u = n & 255, w = u >> 4, r = u & 15;
  for (int k = threadIdx.x; k < 544; k += 256) {
    int kt = k >> 5, kk = k & 31, q = kk >> 3, j = kk & 7;
    float val;
    if (k < 256) val = Wih0[n * 259 + k];
    else if (k < 512) val = Whh0[n * 256 + (k - 256)];
    else if (k < 515) val = Wih0[n * 259 + 256 + (k - 512)];
    else val = 0.0f;
    W0p[((((w * 17 + kt) * 4 + c) * 64) + q * 16 + r) * 8 + j] = (_Float16)val;
  }
  for (int k = threadIdx.x; k < 512; k += 256) {
    int kt = k >> 5, kk = k & 31, q = kk >> 3, j = kk & 7;
    float val = (k < 256) ? Wih1[n * 256 + k] : Whh1[n * 256 + (k - 256)];
    W1p[((((w * 16 + kt) * 4 + c) * 64) + q * 16 + r) * 8 + j] = (_Float16)val;
  }
  if (threadIdx.x == 0) { b0[n] = bih0[n] + bhh0[n]; b1[n] = bih1[n] + bhh1[n]; }
}

// 16 waves per WG (4/SIMD). Wave w owns units [w*16, w*16+16) x all 4 gates.
// 33 weight K-tiles/step (17 L0 + 16 L1) streamed through THREE STATICALLY-NAMED
// quad-buffers Q0/Q1/Q2 (literal indices only -> registers, never scratch; rule #20).
// Straight-line macro-expanded schedule, prefetch distance 3, loads cross the
// LDS-only barriers (vmcnt never drained inside the loop).
__global__ __launch_bounds__(1024, 4)
void noteaxis_main(const float* __restrict__ nf, const float* __restrict__ cond,
                   const _Float16* __restrict__ W0p, const _Float16* __restrict__ W1p,
                   const float* __restrict__ b0g, const float* __restrict__ b1g,
                   const float* __restrict__ Wout, const float* __restrict__ bout,
                   float* __restrict__ out) {
  __shared__ __align__(16) _Float16 lds_x[MT][LDX];
  __shared__ __align__(16) _Float16 lds_h0[MT][LDH0];
  __shared__ __align__(16) _Float16 lds_h1[MT][LDH1];
  __shared__ float lds_part[16][MT][3];

  const int tid = threadIdx.x;
  const int w = tid >> 6;        // wave 0..15: unit slice
  const int lane = tid & 63;
  const int r = lane & 15;       // A row = batch row; D col = unit-within-slice
  const int q = lane >> 4;       // k sub-chunk / D row group
  const int u = w * 16 + r;      // this lane's unit column
  const int row0 = blockIdx.x * MT;

  for (int i = tid; i < MT * LDH0; i += 1024) ((_Float16*)lds_h0)[i] = (_Float16)0.0f;
  for (int i = tid; i < MT * LDH1; i += 1024) ((_Float16*)lds_h1)[i] = (_Float16)0.0f;

  float b0c[4], b1c[4];
#pragma unroll
  for (int c = 0; c < 4; ++c) { b0c[c] = b0g[c * 256 + u]; b1c[c] = b1g[c * 256 + u]; }
  const float wov0 = Wout[u], wov1 = Wout[256 + u], wov2 = Wout[512 + u];
  const float bo0 = bout[0], bo1 = bout[1], bo2 = bout[2];

  float c0s[4], c1s[4];
#pragma unroll
  for (int g = 0; g < 4; ++g) { c0s[g] = 0.0f; c1s[g] = 0.0f; }

  const _Float16* pW0 = W0p + (size_t)w * (17 * 4 * 512) + lane * 8;
  const _Float16* pW1 = W1p + (size_t)w * (16 * 4 * 512) + lane * 8;

  f32x4 acc[4];
  half8 Q0[4], Q1[4], Q2[4];     // statically-named rotating quad-buffers

// load weight tile with global step-invariant id nt (0..16 = L0, 17..32 = L1)
// into Q<B>. nt is ALWAYS a literal -> ternary folds, indices static.
#define LOADT(B, nt) do {                                                          \
    const _Float16* _b = ((nt) < 17) ? (pW0 + (size_t)(nt) * 2048)                 \
                                     : (pW1 + (size_t)((nt) - 17) * 2048);         \
    Q##B[0] = *(const half8*)_b;                                                   \
    Q##B[1] = *(const half8*)(_b + 512);                                           \
    Q##B[2] = *(const half8*)(_b + 1024);                                          \
    Q##B[3] = *(const half8*)(_b + 1536);                                          \
  } while (0)

#define MFMAQ(B, a_) do {                                                          \
    acc[0] = __builtin_amdgcn_mfma_f32_16x16x32_f16((a_), Q##B[0], acc[0], 0, 0, 0); \
    acc[1] = __builtin_amdgcn_mfma_f32_16x16x32_f16((a_), Q##B[1], acc[1], 0, 0, 0); \
    acc[2] = __builtin_amdgcn_mfma_f32_16x16x32_f16((a_), Q##B[2], acc[2], 0, 0, 0); \
    acc[3] = __builtin_amdgcn_mfma_f32_16x16x32_f16((a_), Q##B[3], acc[3], 0, 0, 0); \
  } while (0)

// A fragments (t literal -> ternaries fold)
#define A0F(t) ((t) < 8  ? *(const half8*)&lds_x[r][(t) * 32 + q * 8]              \
              : (t) < 16 ? *(const half8*)&lds_h0[r][((t) - 8) * 32 + q * 8]       \
                         : *(const half8*)&lds_h0[r][256 + q * 8])
#define A1F(t) ((t) < 8  ? *(const half8*)&lds_h0[r][(t) * 32 + q * 8]             \
                         : *(const half8*)&lds_h1[r][((t) - 8) * 32 + q * 8])

// P1 step: consume L0 tile t from Q<B>, refill Q<B> with tile t+3
#define P1S(t, B) do { half8 _a = A0F(t); MFMAQ(B, _a); LOADT(B, (t) + 3); } while (0)
// P3 step: consume L1 tile t (global id 17+t) from Q<B>, refill with id (t+20)%33
#define P3S(t, B) do { half8 _a = A1F(t); MFMAQ(B, _a); LOADT(B, ((t) + 20) % 33); } while (0)

  // prologue: stage x(0) (sn(0)=0 via zero-init)
  {
    const float4 xv0 = *(const float4*)(nf + ((size_t)(row0 + w) * NSTEP + 0) * 256 + lane * 4);
    half4 hx = { (_Float16)xv0.x, (_Float16)xv0.y, (_Float16)xv0.z, (_Float16)xv0.w };
    *(half4*)&lds_x[w][lane * 4] = hx;
  }
  __syncthreads();

  LOADT(0, 0); LOADT(1, 1); LOADT(2, 2);

#pragma unroll 1
  for (int n = 0; n < NSTEP; ++n) {
    // issue next-step staging loads EARLY so their vmcnt wait (in P2) sits
    // behind this step's weight loads instead of draining them.
    const int np = (n + 1 < NSTEP) ? n + 1 : n;
    const float4 xv = *(const float4*)(nf + ((size_t)(row0 + w) * NSTEP + np) * 256 + lane * 4);
    float s0 = 0.f, s1 = 0.f, s2 = 0.f;
    if (tid < MT) {
      const float* cp = cond + ((size_t)(row0 + tid) * NSTEP + n) * 3;   // sn(n+1) = cond[n]
      s0 = cp[0]; s1 = cp[1]; s2 = cp[2];
    }

    // ---- P1: layer 0, 17 K-tiles (8 x | 8 h0 | 1 sn-ext) ----
#pragma unroll
    for (int c = 0; c < 4; ++c) { f32x4 bz = {b0c[c], b0c[c], b0c[c], b0c[c]}; acc[c] = bz; }

    __builtin_amdgcn_s_setprio(1);
    P1S(0, 0);  P1S(1, 1);  P1S(2, 2);
    P1S(3, 0);  P1S(4, 1);  P1S(5, 2);
    P1S(6, 0);  P1S(7, 1);  P1S(8, 2);
    P1S(9, 0);  P1S(10, 1); P1S(11, 2);
    P1S(12, 0); P1S(13, 1); P1S(14, 2);   // t=14 refills with id 17 = L1 tile 0
    P1S(15, 0); P1S(16, 1);               // refills ids 18,19 = L1 tiles 1,2
    __builtin_amdgcn_s_setprio(0);

    BAR();  // B1: all waves done reading lds_x(n), lds_h0(n-1)+ext

    // ---- P2: cell 0 + stage x(n+1)/sn(n+1) + store out(n-1) ----
#pragma unroll
    for (int g = 0; g < 4; ++g) {
      float i_ = acc[0][g], f_ = acc[1][g], g_ = acc[2][g], o_ = acc[3][g];
      float cc = sigm(f_) * c0s[g] + sigm(i_) * tanh_f(g_);
      c0s[g] = cc;
      lds_h0[q * 4 + g][u] = (_Float16)(sigm(o_) * tanh_f(cc));
    }
    {
      half4 hx = { (_Float16)xv.x, (_Float16)xv.y, (_Float16)xv.z, (_Float16)xv.w };
      *(half4*)&lds_x[w][lane * 4] = hx;
    }
    if (tid < MT) {
      lds_h0[tid][256] = (_Float16)s0;
      lds_h0[tid][257] = (_Float16)s1;
      lds_h0[tid][258] = (_Float16)s2;
    }
    if (n > 0 && tid < MT * 3) {
      int m = tid / 3, ch = tid - m * 3;
      float s = (ch == 0 ? bo0 : (ch == 1 ? bo1 : bo2));
#pragma unroll
      for (int ww = 0; ww < 16; ++ww) s += lds_part[ww][m][ch];
      if (ch < 2) s = 1.0f / (1.0f + __expf(-s));
      out[((size_t)(row0 + m) * NSTEP + (n - 1)) * 3 + ch] = s;
    }

    BAR();  // B2: h0(n), x(n+1), sn(n+1) visible

    // ---- P3: layer 1, 16 K-tiles (8 h0new | 8 h1) ----
#pragma unroll
    for (int c = 0; c < 4; ++c) { f32x4 bz = {b1c[c], b1c[c], b1c[c], b1c[c]}; acc[c] = bz; }

    __builtin_amdgcn_s_setprio(1);
    P3S(0, 2);  P3S(1, 0);  P3S(2, 1);
    P3S(3, 2);  P3S(4, 0);  P3S(5, 1);
    P3S(6, 2);  P3S(7, 0);  P3S(8, 1);
    P3S(9, 2);  P3S(10, 0); P3S(11, 1);
    P3S(12, 2);                            // refills id 32 = L1 tile 15
    P3S(13, 0); P3S(14, 1); P3S(15, 2);    // refill ids wrap: 33,34,35 -> 0,1,2 (next-step L0)
    __builtin_amdgcn_s_setprio(0);

    BAR();  // B3: all waves done reading lds_h0(n), lds_h1(n-1)

    // ---- P4: cell 1 + output partials (no barrier; B1(n+1) covers visibility) ----
    float part[4][3];
#pragma unroll
    for (int g = 0; g < 4; ++g) {
      float i_ = acc[0][g], f_ = acc[1][g], g_ = acc[2][g], o_ = acc[3][g];
      float cc = sigm(f_) * c1s[g] + sigm(i_) * tanh_f(g_);
      c1s[g] = cc;
      float hh = sigm(o_) * tanh_f(cc);
      lds_h1[q * 4 + g][u] = (_Float16)hh;
      part[g][0] = hh * wov0;
      part[g][1] = hh * wov1;
      part[g][2] = hh * wov2;
    }
#pragma unroll
    for (int g = 0; g < 4; ++g)
#pragma unroll
      for (int ch = 0; ch < 3; ++ch) {
        float p = part[g][ch];
        p += __shfl_xor(p, 1);
        p += __shfl_xor(p, 2);
        p += __shfl_xor(p, 4);
        p += __shfl_xor(p, 8);
        part[g][ch] = p;
      }
    if (r == 0) {
#pragma unroll
      for (int g = 0; g < 4; ++g) {
        int m = q * 4 + g;
        lds_part[w][m][0] = part[g][0];
        lds_part[w][m][1] = part[g][1];
        lds_part[w][m][2] = part[g][2];
      }
    }
  }

  BAR();
  if (tid < MT * 3) {
    int m = tid / 3, ch = tid - m * 3;
    float s = (ch == 0 ? bo0 : (ch == 1 ? bo1 : bo2));
#pragma unroll
    for (int ww = 0; ww < 16; ++ww) s += lds_part[ww][m][ch];
    if (ch < 2) s = 1.0f / (1.0f + __expf(-s));
    out[((size_t)(row0 + m) * NSTEP + (NSTEP - 1)) * 3 + ch] = s;
  }
}

extern "C" void kernel_launch(void* const* d_in, const int* in_sizes, int n_in,
                              void* d_out, int out_size, void* d_ws, size_t ws_size,
                              hipStream_t stream) {
  const float* nf   = (const float*)d_in[0];
  const float* cond = (const float*)d_in[1];
  const float* Wih0 = (const float*)d_in[2];
  const float* Whh0 = (const float*)d_in[3];
  const float* bih0 = (const float*)d_in[4];
  const float* bhh0 = (const float*)d_in[5];
  const float* Wih1 = (const float*)d_in[6];
  const float* Whh1 = (const float*)d_in[7];
  const float* bih1 = (const float*)d_in[8];
  const float* bhh1 = (const float*)d_in[9];
  const float* Wout = (const float*)d_in[10];
  const float* bout = (const float*)d_in[11];
  float* out = (float*)d_out;

  _Float16* W0p = (_Float16*)d_ws;                 // 16*17*4*512 = 557056 halfs
  _Float16* W1p = W0p + 16 * 17 * 4 * 512;         // 16*16*4*512 = 524288 halfs
  float* b0 = (float*)(W1p + 16 * 16 * 4 * 512);   // 4 KB
  float* b1 = b0 + 1024;                           // 4 KB

  prep_weights<<<1024, 256, 0, stream>>>(Wih0, Whh0, bih0, bhh0, Wih1, Whh1, bih1, bhh1, W0p, W1p, b0, b1);
  noteaxis_main<<<256, 1024, 0, stream>>>(nf, cond, W0p, W1p, b0, b1, Wout, bout, out);
}

// Round 5
// 5139.733 us; speedup vs baseline: 1.0039x; 1.0039x over previous
//
#include <hip/hip_runtime.h>

typedef _Float16 half8 __attribute__((ext_vector_type(8)));
typedef _Float16 half4 __attribute__((ext_vector_type(4)));
typedef float f32x4 __attribute__((ext_vector_type(4)));

#define NSTEP 48
#define MT 16
#define LDX 264    // x row stride (halfs)
#define LDH0 296   // h0 + ext(sn+zeros) row stride
#define LDH1 264

// LDS-only barrier: does NOT drain vmcnt -> weight prefetch stays in flight.
// sched_barrier(0) fences compiler reordering around the inline-asm wait.
#define BAR() do { asm volatile("s_waitcnt lgkmcnt(0)" ::: "memory"); \
                   __builtin_amdgcn_s_barrier();                      \
                   __builtin_amdgcn_sched_barrier(0); } while (0)

__device__ __forceinline__ float sigm(float x) { return 1.0f / (1.0f + __expf(-x)); }
__device__ __forceinline__ float tanh_f(float x) {
  float ax = fabsf(x);
  float e = __expf(-2.0f * ax);
  float t = (1.0f - e) / (1.0f + e);
  return copysignf(t, x);
}

// Fragment-order packed weights (coalesced: one 1KB contiguous block per (w,kt,c)):
//   W0p[w][kt(17)][c(4)][lane(64)=(q<<4|r)][j(8)] = W0[c*256 + w*16 + r][kt*32 + q*8 + j]
//     where W0 K-layout = [256 x-feat | 256 h0 | 3 shifted-notes | 29 zeros]
//   W1p[w][kt(16)][c][lane][j] = W1[c*256 + w*16 + r][kt*32 + q*8 + j], K = [256 h0new | 256 h1]
__global__ void prep_weights(const float* __restrict__ Wih0, const float* __restrict__ Whh0,
                             const float* __restrict__ bih0, const float* __restrict__ bhh0,
                             const float* __restrict__ Wih1, const float* __restrict__ Whh1,
                             const float* __restrict__ bih1, const float* __restrict__ bhh1,
                             _Float16* __restrict__ W0p, _Float16* __restrict__ W1p,
                             float* __restrict__ b0, float* __restrict__ b1) {
  int n = blockIdx.x;              // gate-row 0..1023
  int c = n >> 8, u = n & 255, w = u >> 4, r = u & 15;
  for (int k = threadIdx.x; k < 544; k += 256) {
    int kt = k >> 5, kk = k & 31, q = kk >> 3, j = kk & 7;
    float val;
    if (k < 256) val = Wih0[n * 259 + k];
    else if (k < 512) val = Whh0[n * 256 + (k - 256)];
    else if (k < 515) val = Wih0[n * 259 + 256 + (k - 512)];
    else val = 0.0f;
    W0p[((((w * 17 + kt) * 4 + c) * 64) + q * 16 + r) * 8 + j] = (_Float16)val;
  }
  for (int k = threadIdx.x; k < 512; k += 256) {
    int kt = k >> 5, kk = k & 31, q = kk >> 3, j = kk & 7;
    float val = (k < 256) ? Wih1[n * 256 + k] : Whh1[n * 256 + (k - 256)];
    W1p[((((w * 16 + kt) * 4 + c) * 64) + q * 16 + r) * 8 + j] = (_Float16)val;
  }
  if (threadIdx.x == 0) { b0[n] = bih0[n] + bhh0[n]; b1[n] = bih1[n] + bhh1[n]; }
}

// 16 waves per WG (4/SIMD). Wave w owns units [w*16, w*16+16) x all 4 gates.
// 33 weight K-tiles/step (17 L0 + 16 L1) streamed through three statically-named
// quad-buffers Q0/Q1/Q2, prefetch distance 3, loads cross the LDS-only barriers.
// __launch_bounds__(1024, 1): ONE 16-wave block per CU -> VGPR cap 128.
// (With arg2=4 the toolchain capped VGPRs at 64 -> ~30 regs spilled -> scratch
//  thrashed L2 -> 41% weight-fetch miss to HBM. R3/R4 evidence.)
__global__ __launch_bounds__(1024, 1)
void noteaxis_main(const float* __restrict__ nf, const float* __restrict__ cond,
                   const _Float16* __restrict__ W0p, const _Float16* __restrict__ W1p,
                   const float* __restrict__ b0g, const float* __restrict__ b1g,
                   const float* __restrict__ Wout, const float* __restrict__ bout,
                   float* __restrict__ out) {
  __shared__ __align__(16) _Float16 lds_x[MT][LDX];
  __shared__ __align__(16) _Float16 lds_h0[MT][LDH0];
  __shared__ __align__(16) _Float16 lds_h1[MT][LDH1];
  __shared__ float lds_part[16][MT][3];

  const int tid = threadIdx.x;
  const int w = tid >> 6;        // wave 0..15: unit slice
  const int lane = tid & 63;
  const int r = lane & 15;       // A row = batch row; D col = unit-within-slice
  const int q = lane >> 4;       // k sub-chunk / D row group
  const int u = w * 16 + r;      // this lane's unit column
  const int row0 = blockIdx.x * MT;

  for (int i = tid; i < MT * LDH0; i += 1024) ((_Float16*)lds_h0)[i] = (_Float16)0.0f;
  for (int i = tid; i < MT * LDH1; i += 1024) ((_Float16*)lds_h1)[i] = (_Float16)0.0f;

  float b0c[4], b1c[4];
#pragma unroll
  for (int c = 0; c < 4; ++c) { b0c[c] = b0g[c * 256 + u]; b1c[c] = b1g[c * 256 + u]; }
  const float wov0 = Wout[u], wov1 = Wout[256 + u], wov2 = Wout[512 + u];
  const float bo0 = bout[0], bo1 = bout[1], bo2 = bout[2];

  float c0s[4], c1s[4];
#pragma unroll
  for (int g = 0; g < 4; ++g) { c0s[g] = 0.0f; c1s[g] = 0.0f; }

  const _Float16* pW0 = W0p + (size_t)w * (17 * 4 * 512) + lane * 8;
  const _Float16* pW1 = W1p + (size_t)w * (16 * 4 * 512) + lane * 8;

  f32x4 acc[4];
  half8 Q0[4], Q1[4], Q2[4];     // statically-named rotating quad-buffers

// load weight tile with global step-invariant id nt (0..16 = L0, 17..32 = L1)
// into Q<B>. nt is ALWAYS a literal -> ternary folds, indices static.
#define LOADT(B, nt) do {                                                          \
    const _Float16* _b = ((nt) < 17) ? (pW0 + (size_t)(nt) * 2048)                 \
                                     : (pW1 + (size_t)((nt) - 17) * 2048);         \
    Q##B[0] = *(const half8*)_b;                                                   \
    Q##B[1] = *(const half8*)(_b + 512);                                           \
    Q##B[2] = *(const half8*)(_b + 1024);                                          \
    Q##B[3] = *(const half8*)(_b + 1536);                                          \
  } while (0)

#define MFMAQ(B, a_) do {                                                          \
    acc[0] = __builtin_amdgcn_mfma_f32_16x16x32_f16((a_), Q##B[0], acc[0], 0, 0, 0); \
    acc[1] = __builtin_amdgcn_mfma_f32_16x16x32_f16((a_), Q##B[1], acc[1], 0, 0, 0); \
    acc[2] = __builtin_amdgcn_mfma_f32_16x16x32_f16((a_), Q##B[2], acc[2], 0, 0, 0); \
    acc[3] = __builtin_amdgcn_mfma_f32_16x16x32_f16((a_), Q##B[3], acc[3], 0, 0, 0); \
  } while (0)

// A fragments (t literal -> ternaries fold)
#define A0F(t) ((t) < 8  ? *(const half8*)&lds_x[r][(t) * 32 + q * 8]              \
              : (t) < 16 ? *(const half8*)&lds_h0[r][((t) - 8) * 32 + q * 8]       \
                         : *(const half8*)&lds_h0[r][256 + q * 8])
#define A1F(t) ((t) < 8  ? *(const half8*)&lds_h0[r][(t) * 32 + q * 8]             \
                         : *(const half8*)&lds_h1[r][((t) - 8) * 32 + q * 8])

// P1 step: consume L0 tile t from Q<B>, refill Q<B> with tile t+3
#define P1S(t, B) do { half8 _a = A0F(t); MFMAQ(B, _a); LOADT(B, (t) + 3); } while (0)
// P3 step: consume L1 tile t (global id 17+t) from Q<B>, refill with id (t+20)%33
#define P3S(t, B) do { half8 _a = A1F(t); MFMAQ(B, _a); LOADT(B, ((t) + 20) % 33); } while (0)

  // prologue: stage x(0) (sn(0)=0 via zero-init)
  {
    const float4 xv0 = *(const float4*)(nf + ((size_t)(row0 + w) * NSTEP + 0) * 256 + lane * 4);
    half4 hx = { (_Float16)xv0.x, (_Float16)xv0.y, (_Float16)xv0.z, (_Float16)xv0.w };
    *(half4*)&lds_x[w][lane * 4] = hx;
  }
  __syncthreads();

  LOADT(0, 0); LOADT(1, 1); LOADT(2, 2);

#pragma unroll 1
  for (int n = 0; n < NSTEP; ++n) {
    // issue next-step staging loads EARLY so their vmcnt wait (in P2) sits
    // behind this step's weight loads instead of draining them.
    const int np = (n + 1 < NSTEP) ? n + 1 : n;
    const float4 xv = *(const float4*)(nf + ((size_t)(row0 + w) * NSTEP + np) * 256 + lane * 4);
    float s0 = 0.f, s1 = 0.f, s2 = 0.f;
    if (tid < MT) {
      const float* cp = cond + ((size_t)(row0 + tid) * NSTEP + n) * 3;   // sn(n+1) = cond[n]
      s0 = cp[0]; s1 = cp[1]; s2 = cp[2];
    }

    // ---- P1: layer 0, 17 K-tiles (8 x | 8 h0 | 1 sn-ext) ----
#pragma unroll
    for (int c = 0; c < 4; ++c) { f32x4 bz = {b0c[c], b0c[c], b0c[c], b0c[c]}; acc[c] = bz; }

    __builtin_amdgcn_s_setprio(1);
    P1S(0, 0);  P1S(1, 1);  P1S(2, 2);
    P1S(3, 0);  P1S(4, 1);  P1S(5, 2);
    P1S(6, 0);  P1S(7, 1);  P1S(8, 2);
    P1S(9, 0);  P1S(10, 1); P1S(11, 2);
    P1S(12, 0); P1S(13, 1); P1S(14, 2);   // t=14 refills with id 17 = L1 tile 0
    P1S(15, 0); P1S(16, 1);               // refills ids 18,19 = L1 tiles 1,2
    __builtin_amdgcn_s_setprio(0);

    BAR();  // B1: all waves done reading lds_x(n), lds_h0(n-1)+ext

    // ---- P2: cell 0 + stage x(n+1)/sn(n+1) + store out(n-1) ----
#pragma unroll
    for (int g = 0; g < 4; ++g) {
      float i_ = acc[0][g], f_ = acc[1][g], g_ = acc[2][g], o_ = acc[3][g];
      float cc = sigm(f_) * c0s[g] + sigm(i_) * tanh_f(g_);
      c0s[g] = cc;
      lds_h0[q * 4 + g][u] = (_Float16)(sigm(o_) * tanh_f(cc));
    }
    {
      half4 hx = { (_Float16)xv.x, (_Float16)xv.y, (_Float16)xv.z, (_Float16)xv.w };
      *(half4*)&lds_x[w][lane * 4] = hx;
    }
    if (tid < MT) {
      lds_h0[tid][256] = (_Float16)s0;
      lds_h0[tid][257] = (_Float16)s1;
      lds_h0[tid][258] = (_Float16)s2;
    }
    if (n > 0 && tid < MT * 3) {
      int m = tid / 3, ch = tid - m * 3;
      float s = (ch == 0 ? bo0 : (ch == 1 ? bo1 : bo2));
#pragma unroll
      for (int ww = 0; ww < 16; ++ww) s += lds_part[ww][m][ch];
      if (ch < 2) s = 1.0f / (1.0f + __expf(-s));
      out[((size_t)(row0 + m) * NSTEP + (n - 1)) * 3 + ch] = s;
    }

    BAR();  // B2: h0(n), x(n+1), sn(n+1) visible

    // ---- P3: layer 1, 16 K-tiles (8 h0new | 8 h1) ----
#pragma unroll
    for (int c = 0; c < 4; ++c) { f32x4 bz = {b1c[c], b1c[c], b1c[c], b1c[c]}; acc[c] = bz; }

    __builtin_amdgcn_s_setprio(1);
    P3S(0, 2);  P3S(1, 0);  P3S(2, 1);
    P3S(3, 2);  P3S(4, 0);  P3S(5, 1);
    P3S(6, 2);  P3S(7, 0);  P3S(8, 1);
    P3S(9, 2);  P3S(10, 0); P3S(11, 1);
    P3S(12, 2);                            // refills id 32 = L1 tile 15
    P3S(13, 0); P3S(14, 1); P3S(15, 2);    // refill ids wrap: 33,34,35 -> 0,1,2 (next-step L0)
    __builtin_amdgcn_s_setprio(0);

    BAR();  // B3: all waves done reading lds_h0(n), lds_h1(n-1)

    // ---- P4: cell 1 + output partials (no barrier; B1(n+1) covers visibility) ----
    float part[4][3];
#pragma unroll
    for (int g = 0; g < 4; ++g) {
      float i_ = acc[0][g], f_ = acc[1][g], g_ = acc[2][g], o_ = acc[3][g];
      float cc = sigm(f_) * c1s[g] + sigm(i_) * tanh_f(g_);
      c1s[g] = cc;
      float hh = sigm(o_) * tanh_f(cc);
      lds_h1[q * 4 + g][u] = (_Float16)hh;
      part[g][0] = hh * wov0;
      part[g][1] = hh * wov1;
      part[g][2] = hh * wov2;
    }
#pragma unroll
    for (int g = 0; g < 4; ++g)
#pragma unroll
      for (int ch = 0; ch < 3; ++ch) {
        float p = part[g][ch];
        p += __shfl_xor(p, 1);
        p += __shfl_xor(p, 2);
        p += __shfl_xor(p, 4);
        p += __shfl_xor(p, 8);
        part[g][ch] = p;
      }
    if (r == 0) {
#pragma unroll
      for (int g = 0; g < 4; ++g) {
        int m = q * 4 + g;
        lds_part[w][m][0] = part[g][0];
        lds_part[w][m][1] = part[g][1];
        lds_part[w][m][2] = part[g][2];
      }
    }
  }

  BAR();
  if (tid < MT * 3) {
    int m = tid / 3, ch = tid - m * 3;
    float s = (ch == 0 ? bo0 : (ch == 1 ? bo1 : bo2));
#pragma unroll
    for (int ww = 0; ww < 16; ++ww) s += lds_part[ww][m][ch];
    if (ch < 2) s = 1.0f / (1.0f + __expf(-s));
    out[((size_t)(row0 + m) * NSTEP + (NSTEP - 1)) * 3 + ch] = s;
  }
}

extern "C" void kernel_launch(void* const* d_in, const int* in_sizes, int n_in,
                              void* d_out, int out_size, void* d_ws, size_t ws_size,
                              hipStream_t stream) {
  const float* nf   = (const float*)d_in[0];
  const float* cond = (const float*)d_in[1];
  const float* Wih0 = (const float*)d_in[2];
  const float* Whh0 = (const float*)d_in[3];
  const float* bih0 = (const float*)d_in[4];
  const float* bhh0 = (const float*)d_in[5];
  const float* Wih1 = (const float*)d_in[6];
  const float* Whh1 = (const float*)d_in[7];
  const float* bih1 = (const float*)d_in[8];
  const float* bhh1 = (const float*)d_in[9];
  const float* Wout = (const float*)d_in[10];
  const float* bout = (const float*)d_in[11];
  float* out = (float*)d_out;

  _Float16* W0p = (_Float16*)d_ws;                 // 16*17*4*512 = 557056 halfs
  _Float16* W1p = W0p + 16 * 17 * 4 * 512;         // 16*16*4*512 = 524288 halfs
  float* b0 = (float*)(W1p + 16 * 16 * 4 * 512);   // 4 KB
  float* b1 = b0 + 1024;                           // 4 KB

  prep_weights<<<1024, 256, 0, stream>>>(Wih0, Whh0, bih0, bhh0, Wih1, Whh1, bih1, bhh1, W0p, W1p, b0, b1);
  noteaxis_main<<<256, 1024, 0, stream>>>(nf, cond, W0p, W1p, b0, b1, Wout, bout, out);
}

// Round 6
// 4595.266 us; speedup vs baseline: 1.1229x; 1.1185x over previous
//
#include <hip/hip_runtime.h>

typedef _Float16 half8 __attribute__((ext_vector_type(8)));
typedef _Float16 half4 __attribute__((ext_vector_type(4)));
typedef float f32x4 __attribute__((ext_vector_type(4)));

#define NSTEP 48
#define MT 16
#define LDX 264    // x row stride (halfs)
#define LDH0 296   // h0 + ext(sn+zeros) row stride
#define LDH1 264

// LDS-only barrier: does NOT drain vmcnt -> weight prefetch stays in flight.
#define BAR() do { asm volatile("s_waitcnt lgkmcnt(0)" ::: "memory"); \
                   __builtin_amdgcn_s_barrier();                      \
                   __builtin_amdgcn_sched_barrier(0); } while (0)

__device__ __forceinline__ float sigm(float x) { return 1.0f / (1.0f + __expf(-x)); }
__device__ __forceinline__ float tanh_f(float x) {
  float ax = fabsf(x);
  float e = __expf(-2.0f * ax);
  float t = (1.0f - e) / (1.0f + e);
  return copysignf(t, x);
}

// Unified fragment-order packed weights, per-wave contiguous:
//   Wp[w][t(33)][c(4)][lane(64)=(q<<4|r)][j(8)]
//   t=0..16  : layer-0 K-tiles over K-layout [256 x | 256 h0 | 3 sn | 29 zeros]
//   t=17..32 : layer-1 K-tiles over K-layout [256 h0new | 256 h1]
//   value = W[c*256 + w*16 + r][t_local*32 + q*8 + j]
__global__ void prep_weights(const float* __restrict__ Wih0, const float* __restrict__ Whh0,
                             const float* __restrict__ bih0, const float* __restrict__ bhh0,
                             const float* __restrict__ Wih1, const float* __restrict__ Whh1,
                             const float* __restrict__ bih1, const float* __restrict__ bhh1,
                             _Float16* __restrict__ Wp,
                             float* __restrict__ b0, float* __restrict__ b1) {
  int n = blockIdx.x;              // gate-row 0..1023
  int c = n >> 8, u = n & 255, w = u >> 4, r = u & 15;
  for (int k = threadIdx.x; k < 544; k += 256) {
    int t = k >> 5, kk = k & 31, q = kk >> 3, j = kk & 7;
    float val;
    if (k < 256) val = Wih0[n * 259 + k];
    else if (k < 512) val = Whh0[n * 256 + (k - 256)];
    else if (k < 515) val = Wih0[n * 259 + 256 + (k - 512)];
    else val = 0.0f;
    Wp[(((size_t)w * 33 + t) * 4 + c) * 512 + (size_t)(q * 16 + r) * 8 + j] = (_Float16)val;
  }
  for (int k = threadIdx.x; k < 512; k += 256) {
    int t = 17 + (k >> 5), kk = k & 31, q = kk >> 3, j = kk & 7;
    float val = (k < 256) ? Wih1[n * 256 + k] : Whh1[n * 256 + (k - 256)];
    Wp[(((size_t)w * 33 + t) * 4 + c) * 512 + (size_t)(q * 16 + r) * 8 + j] = (_Float16)val;
  }
  if (threadIdx.x == 0) { b0[n] = bih0[n] + bhh0[n]; b1[n] = bih1[n] + bhh1[n]; }
}

// 16 waves per WG (1 WG/CU). Wave w owns units [w*16, w*16+16) x 4 gates.
// 33 weight K-tiles/step streamed through TWO statically-named quad-buffers
// (depth-2: 8 b128 in flight/wave; total live regs ~95 of the 128/wave unified
// budget at 16 waves/CU -- R1-proven pressure, no spill). Tile parity flips per
// step (33 odd), so the note loop is unrolled 2x with buffer roles swapped.
// Weight loads cross the LDS-only barriers; vmcnt is never drained in the loop.
__global__ __launch_bounds__(1024, 4)
void noteaxis_main(const float* __restrict__ nf, const float* __restrict__ cond,
                   const _Float16* __restrict__ Wp,
                   const float* __restrict__ b0g, const float* __restrict__ b1g,
                   const float* __restrict__ Wout, const float* __restrict__ bout,
                   float* __restrict__ out) {
  __shared__ __align__(16) _Float16 lds_x[MT][LDX];
  __shared__ __align__(16) _Float16 lds_h0[MT][LDH0];
  __shared__ __align__(16) _Float16 lds_h1[MT][LDH1];
  __shared__ float lds_part[16][MT][3];

  const int tid = threadIdx.x;
  const int w = tid >> 6;        // wave 0..15: unit slice
  const int lane = tid & 63;
  const int r = lane & 15;       // A row = batch row; D col = unit-within-slice
  const int q = lane >> 4;       // k sub-chunk / D row group
  const int u = w * 16 + r;      // this lane's unit column
  const int row0 = blockIdx.x * MT;

  for (int i = tid; i < MT * LDH0; i += 1024) ((_Float16*)lds_h0)[i] = (_Float16)0.0f;
  for (int i = tid; i < MT * LDH1; i += 1024) ((_Float16*)lds_h1)[i] = (_Float16)0.0f;

  float b0c[4], b1c[4];
#pragma unroll
  for (int c = 0; c < 4; ++c) { b0c[c] = b0g[c * 256 + u]; b1c[c] = b1g[c * 256 + u]; }
  const float wov0 = Wout[u], wov1 = Wout[256 + u], wov2 = Wout[512 + u];
  const float bo0 = bout[0], bo1 = bout[1], bo2 = bout[2];

  float c0s[4], c1s[4];
#pragma unroll
  for (int g = 0; g < 4; ++g) { c0s[g] = 0.0f; c1s[g] = 0.0f; }

  f32x4 acc[4];
  half8 QA[4], QB[4];            // statically-named depth-2 quad-buffers

// load one K-tile (4x b128, offsets 0/1024/2048/3072 B fit imm13) from running ptr
#define LOADT(BUF_, P_) do {                                                       \
    BUF_[0] = *(const half8*)(P_);                                                 \
    BUF_[1] = *(const half8*)((P_) + 512);                                         \
    BUF_[2] = *(const half8*)((P_) + 1024);                                        \
    BUF_[3] = *(const half8*)((P_) + 1536);                                        \
  } while (0)

#define MFMAQ(BUF_, a_) do {                                                         \
    acc[0] = __builtin_amdgcn_mfma_f32_16x16x32_f16((a_), BUF_[0], acc[0], 0, 0, 0); \
    acc[1] = __builtin_amdgcn_mfma_f32_16x16x32_f16((a_), BUF_[1], acc[1], 0, 0, 0); \
    acc[2] = __builtin_amdgcn_mfma_f32_16x16x32_f16((a_), BUF_[2], acc[2], 0, 0, 0); \
    acc[3] = __builtin_amdgcn_mfma_f32_16x16x32_f16((a_), BUF_[3], acc[3], 0, 0, 0); \
  } while (0)

// A fragments, t literal
#define A0F(t) ((t) < 8  ? *(const half8*)&lds_x[r][(t) * 32 + q * 8]              \
              : (t) < 16 ? *(const half8*)&lds_h0[r][((t) - 8) * 32 + q * 8]       \
                         : *(const half8*)&lds_h0[r][256 + q * 8])
#define A1F(s) ((s) < 8  ? *(const half8*)&lds_h0[r][(s) * 32 + q * 8]             \
                         : *(const half8*)&lds_h1[r][((s) - 8) * 32 + q * 8])

// pipeline steps: consume tile t from BUF, refill BUF with tile t+2 from running ptr
#define P1T(t, BUF_, P_) do { half8 _a = A0F(t); MFMAQ(BUF_, _a); LOADT(BUF_, P_); P_ += 4096; } while (0)
#define P3T(s, BUF_, P_) do { half8 _a = A1F(s); MFMAQ(BUF_, _a); LOADT(BUF_, P_); P_ += 4096; } while (0)

// One full note-step. Invariant at entry: QA_=tile0 data, QB_=tile1 data,
// PE_->tile2, PO_->tile3. At exit the same invariant holds with roles SWAPPED
// (QB_=tile0, QA_=tile1, PO_->tile2, PE_->tile3) -> call alternately.
#define STEPB(NN_, QA_, QB_, PE_, PO_) do {                                        \
    const int nn = (NN_);                                                          \
    const int np = (nn + 1 < NSTEP) ? nn + 1 : nn;                                 \
    const float4 xv = *(const float4*)(nf + ((size_t)(row0 + w) * NSTEP + np) * 256 + lane * 4); \
    float s0 = 0.f, s1 = 0.f, s2 = 0.f;                                            \
    if (tid < MT) {                                                                \
      const float* cp = cond + ((size_t)(row0 + tid) * NSTEP + nn) * 3;            \
      s0 = cp[0]; s1 = cp[1]; s2 = cp[2];                                          \
    }                                                                              \
    _Pragma("unroll")                                                              \
    for (int c = 0; c < 4; ++c) { f32x4 bz = {b0c[c], b0c[c], b0c[c], b0c[c]}; acc[c] = bz; } \
    __builtin_amdgcn_s_setprio(1);                                                 \
    P1T(0, QA_, PE_);  P1T(1, QB_, PO_);  P1T(2, QA_, PE_);  P1T(3, QB_, PO_);     \
    P1T(4, QA_, PE_);  P1T(5, QB_, PO_);  P1T(6, QA_, PE_);  P1T(7, QB_, PO_);     \
    P1T(8, QA_, PE_);  P1T(9, QB_, PO_);  P1T(10, QA_, PE_); P1T(11, QB_, PO_);    \
    P1T(12, QA_, PE_); P1T(13, QB_, PO_); P1T(14, QA_, PE_); P1T(15, QB_, PO_);    \
    P1T(16, QA_, PE_);                                                             \
    __builtin_amdgcn_s_setprio(0);                                                 \
    BAR();  /* B1: all waves done reading lds_x(n), lds_h0(n-1)+ext */             \
    _Pragma("unroll")                                                              \
    for (int g = 0; g < 4; ++g) {                                                  \
      float i_ = acc[0][g], f_ = acc[1][g], g_ = acc[2][g], o_ = acc[3][g];        \
      float cc = sigm(f_) * c0s[g] + sigm(i_) * tanh_f(g_);                        \
      c0s[g] = cc;                                                                 \
      lds_h0[q * 4 + g][u] = (_Float16)(sigm(o_) * tanh_f(cc));                    \
    }                                                                              \
    {                                                                              \
      half4 hx = { (_Float16)xv.x, (_Float16)xv.y, (_Float16)xv.z, (_Float16)xv.w }; \
      *(half4*)&lds_x[w][lane * 4] = hx;                                           \
    }                                                                              \
    if (tid < MT) {                                                                \
      lds_h0[tid][256] = (_Float16)s0;                                             \
      lds_h0[tid][257] = (_Float16)s1;                                             \
      lds_h0[tid][258] = (_Float16)s2;                                             \
    }                                                                              \
    if (nn > 0 && tid < MT * 3) {                                                  \
      int m = tid / 3, ch = tid - m * 3;                                           \
      float s = (ch == 0 ? bo0 : (ch == 1 ? bo1 : bo2));                           \
      _Pragma("unroll")                                                            \
      for (int ww = 0; ww < 16; ++ww) s += lds_part[ww][m][ch];                    \
      if (ch < 2) s = 1.0f / (1.0f + __expf(-s));                                  \
      out[((size_t)(row0 + m) * NSTEP + (nn - 1)) * 3 + ch] = s;                   \
    }                                                                              \
    BAR();  /* B2: h0(n), x(n+1), sn(n+1) visible */                               \
    _Pragma("unroll")                                                              \
    for (int c = 0; c < 4; ++c) { f32x4 bz = {b1c[c], b1c[c], b1c[c], b1c[c]}; acc[c] = bz; } \
    __builtin_amdgcn_s_setprio(1);                                                 \
    P3T(0, QB_, PO_);  P3T(1, QA_, PE_);  P3T(2, QB_, PO_);  P3T(3, QA_, PE_);     \
    P3T(4, QB_, PO_);  P3T(5, QA_, PE_);  P3T(6, QB_, PO_);  P3T(7, QA_, PE_);     \
    P3T(8, QB_, PO_);  P3T(9, QA_, PE_);  P3T(10, QB_, PO_); P3T(11, QA_, PE_);    \
    P3T(12, QB_, PO_); P3T(13, QA_, PE_);                                          \
    /* s=14 consumes tile31 from QB_, refills with tile0 (wrap: PO_ is at 33) */   \
    { half8 _a = A1F(14); MFMAQ(QB_, _a); PO_ -= 33 * 2048; LOADT(QB_, PO_); PO_ += 4096; } \
    /* s=15 consumes tile32 from QA_, refills with tile1 (wrap: PE_ is at 34) */   \
    { half8 _a = A1F(15); MFMAQ(QA_, _a); PE_ -= 33 * 2048; LOADT(QA_, PE_); PE_ += 4096; } \
    __builtin_amdgcn_s_setprio(0);                                                 \
    BAR();  /* B3: all waves done reading lds_h0(n), lds_h1(n-1) */                \
    float part[4][3];                                                              \
    _Pragma("unroll")                                                              \
    for (int g = 0; g < 4; ++g) {                                                  \
      float i_ = acc[0][g], f_ = acc[1][g], g_ = acc[2][g], o_ = acc[3][g];        \
      float cc = sigm(f_) * c1s[g] + sigm(i_) * tanh_f(g_);                        \
      c1s[g] = cc;                                                                 \
      float hh = sigm(o_) * tanh_f(cc);                                            \
      lds_h1[q * 4 + g][u] = (_Float16)hh;                                         \
      part[g][0] = hh * wov0;                                                      \
      part[g][1] = hh * wov1;                                                      \
      part[g][2] = hh * wov2;                                                      \
    }                                                                              \
    _Pragma("unroll")                                                              \
    for (int g = 0; g < 4; ++g) {                                                  \
      _Pragma("unroll")                                                            \
      for (int ch = 0; ch < 3; ++ch) {                                             \
        float p = part[g][ch];                                                     \
        p += __shfl_xor(p, 1);                                                     \
        p += __shfl_xor(p, 2);                                                     \
        p += __shfl_xor(p, 4);                                                     \
        p += __shfl_xor(p, 8);                                                     \
        part[g][ch] = p;                                                           \
      }                                                                            \
    }                                                                              \
    if (r == 0) {                                                                  \
      _Pragma("unroll")                                                            \
      for (int g = 0; g < 4; ++g) {                                                \
        int m = q * 4 + g;                                                         \
        lds_part[w][m][0] = part[g][0];                                            \
        lds_part[w][m][1] = part[g][1];                                            \
        lds_part[w][m][2] = part[g][2];                                            \
      }                                                                            \
    }                                                                              \
  } while (0)

  // prologue: stage x(0) (sn(0)=0 via zero-init)
  {
    const float4 xv0 = *(const float4*)(nf + ((size_t)(row0 + w) * NSTEP + 0) * 256 + lane * 4);
    half4 hx = { (_Float16)xv0.x, (_Float16)xv0.y, (_Float16)xv0.z, (_Float16)xv0.w };
    *(half4*)&lds_x[w][lane * 4] = hx;
  }
  __syncthreads();

  const _Float16* pE = Wp + (size_t)w * (33 * 2048) + lane * 8;   // tile0
  const _Float16* pO = pE + 2048;                                 // tile1
  LOADT(QA, pE); pE += 4096;   // QA=tile0, pE->tile2
  LOADT(QB, pO); pO += 4096;   // QB=tile1, pO->tile3

#pragma unroll 1
  for (int n = 0; n < NSTEP; n += 2) {
    STEPB(n,     QA, QB, pE, pO);
    STEPB(n + 1, QB, QA, pO, pE);
  }

  BAR();
  if (tid < MT * 3) {
    int m = tid / 3, ch = tid - m * 3;
    float s = (ch == 0 ? bo0 : (ch == 1 ? bo1 : bo2));
#pragma unroll
    for (int ww = 0; ww < 16; ++ww) s += lds_part[ww][m][ch];
    if (ch < 2) s = 1.0f / (1.0f + __expf(-s));
    out[((size_t)(row0 + m) * NSTEP + (NSTEP - 1)) * 3 + ch] = s;
  }
}

extern "C" void kernel_launch(void* const* d_in, const int* in_sizes, int n_in,
                              void* d_out, int out_size, void* d_ws, size_t ws_size,
                              hipStream_t stream) {
  const float* nf   = (const float*)d_in[0];
  const float* cond = (const float*)d_in[1];
  const float* Wih0 = (const float*)d_in[2];
  const float* Whh0 = (const float*)d_in[3];
  const float* bih0 = (const float*)d_in[4];
  const float* bhh0 = (const float*)d_in[5];
  const float* Wih1 = (const float*)d_in[6];
  const float* Whh1 = (const float*)d_in[7];
  const float* bih1 = (const float*)d_in[8];
  const float* bhh1 = (const float*)d_in[9];
  const float* Wout = (const float*)d_in[10];
  const float* bout = (const float*)d_in[11];
  float* out = (float*)d_out;

  _Float16* Wp = (_Float16*)d_ws;                  // 16*33*4*512 = 1081344 halfs
  float* b0 = (float*)(Wp + 16 * 33 * 4 * 512);    // 4 KB
  float* b1 = b0 + 1024;                           // 4 KB

  prep_weights<<<1024, 256, 0, stream>>>(Wih0, Whh0, bih0, bhh0, Wih1, Whh1, bih1, bhh1, Wp, b0, b1);
  noteaxis_main<<<256, 1024, 0, stream>>>(nf, cond, Wp, b0, b1, Wout, bout, out);
}